// Round 10
// baseline (1898.391 us; speedup 1.0000x reference)
//
#include <hip/hip_runtime.h>
#include <cstdint>

// ---------------------------------------------------------------------------
// MaskedDeepRNN fused: 2-layer masked LSTM, B=64 T=512 D_IN=256 H=512 G=2048.
// R9 = R8 (merged k_prep + proven fused t-loop) + PROGRESSIVE SYNC:
//  * per-thread flag poll: thread tid's 8 ring dwords all come from publisher
//    WG (tid>>3); poll only that flag, then read. barA deleted (barB joins).
//    Threads of our own publisher skip the poll (publish drained at barD).
//  * bl1 restage (x[t+1] L0 / h0[t+1] L1) moved to waves 2-3 in the
//    barC->barD window, overlapped with gate math + publish drain.
//  * cross-layer __all poll on wave 3 in the same window. Targets:
//    L0: L1 >= t-7 (slot reuse at t+1); L1: L0 >= t+3 (stage h0[t+2] at t+1).
//    Deadlock-free: both depend only on strictly-older cross progress.
//  * 3 barriers/step (barB, barC, barD).
// Ledger: all-wave poll -700 (R1/R2); 1 WG/CU -200 (R3); scattered publish
// -220 (R4); split-phase +60 (R5); xf16 L2-residency -330 fused (R6);
// per-island weight fold -555 fused (R7, reverted); merged prep +435 (R8).
// ---------------------------------------------------------------------------

typedef _Float16 f16;
typedef _Float16 half8 __attribute__((ext_vector_type(8)));
typedef float floatx4 __attribute__((ext_vector_type(4)));

#define B_ 64
#define T_ 512
#define DIN_ 256
#define H_ 512
#define G_ 2048

// workspace layout (bytes)
static const size_t OFF_FLAGS = 0;                              // 2 lay x 8 isl x 32 flags x 64B = 32 KB
static const size_t OFF_H0B   = 32768;                          // 8 isl x 8 slots x 8KB = 512 KB
static const size_t OFF_H1B   = OFF_H0B + 524288;               // 8 isl x 2 slots x 8KB = 128 KB
static const size_t OFF_WIH0  = OFF_H1B + 131072;               // f16 weights
static const size_t OFF_WHH0  = OFF_WIH0 + (size_t)G_ * DIN_ * 2;
static const size_t OFF_WIH1  = OFF_WHH0 + (size_t)G_ * H_ * 2;
static const size_t OFF_WHH1  = OFF_WIH1 + (size_t)G_ * H_ * 2;
static const size_t OFF_B0    = OFF_WHH1 + (size_t)G_ * H_ * 2;
static const size_t OFF_B1    = OFF_B0 + 8192;
static const size_t OFF_XF16  = OFF_B1 + 8192;                  // 8 isl x 512 t x 8 b x 256 d x 2B
static const size_t XF16_BYTES = (size_t)8 * T_ * 8 * DIN_ * 2; // 16.78 MB
static const size_t ZERO_BYTES = OFF_WIH0;                      // flags + h rings

__device__ __forceinline__ uint32_t ald(const uint32_t* p) {
    return __hip_atomic_load(p, __ATOMIC_RELAXED, __HIP_MEMORY_SCOPE_AGENT);
}
__device__ __forceinline__ void ast(uint32_t* p, uint32_t v) {
    __hip_atomic_store(p, v, __ATOMIC_RELAXED, __HIP_MEMORY_SCOPE_AGENT);
}

// masked f16 half8 from f32 weight + f32 mask (8 consecutive elements)
__device__ __forceinline__ half8 mload(const float* w, const float* m) {
    const float4 a = *(const float4*)w, b = *(const float4*)(w + 4);
    const float4 c = *(const float4*)m, d = *(const float4*)(m + 4);
    half8 h = { (f16)(a.x * c.x), (f16)(a.y * c.y), (f16)(a.z * c.z), (f16)(a.w * c.w),
                (f16)(b.x * d.x), (f16)(b.y * d.y), (f16)(b.z * d.z), (f16)(b.w * d.w) };
    return h;
}

// ------------------------------------------------- merged prep (1 launch) ---
// blocks [0,4096):     xcast  x[b][t][d] f32 -> xf16[isl][t][b&7][d] f16
// blocks [4096,4352):  Wih0*m -> f16
// blocks [4352,4864):  Whh0*m -> f16
// blocks [4864,5376):  Wih1*m -> f16
// blocks [5376,5888):  Whh1*m -> f16
// blocks [5888,5904):  biases
__global__ void k_prep(const float* __restrict__ x, f16* __restrict__ xf16,
                       const float* __restrict__ Wih0, const float* __restrict__ Mih0,
                       const float* __restrict__ Whh0, const float* __restrict__ Mhh0,
                       const float* __restrict__ bih0, const float* __restrict__ bhh0,
                       const float* __restrict__ Wih1, const float* __restrict__ Mih1,
                       const float* __restrict__ Whh1, const float* __restrict__ Mhh1,
                       const float* __restrict__ bih1, const float* __restrict__ bhh1,
                       f16* __restrict__ wih0, f16* __restrict__ whh0,
                       f16* __restrict__ wih1, f16* __restrict__ whh1,
                       float* __restrict__ bs0, float* __restrict__ bs1) {
    const int bid = blockIdx.x, tid = threadIdx.x;
    if (bid < 4096) {
        if (!xf16) return;
        const int isl = bid & 7, t = bid >> 3;
        const int b = tid >> 5, dq = tid & 31;
        const float* s = x + ((size_t)(isl * 8 + b) * T_ + t) * DIN_ + dq * 8;
        const float4 a  = *(const float4*)s;
        const float4 bb = *(const float4*)(s + 4);
        half8 h = { (f16)a.x, (f16)a.y, (f16)a.z, (f16)a.w,
                    (f16)bb.x, (f16)bb.y, (f16)bb.z, (f16)bb.w };
        *(half8*)(xf16 + ((size_t)(isl * 512 + t) * 8 + b) * 256 + dq * 8) = h;
    } else if (bid < 4352) {
        const int i = (bid - 4096) * 256 + tid;
        ((half8*)wih0)[i] = mload(Wih0 + (size_t)i * 8, Mih0 + (size_t)i * 8);
    } else if (bid < 4864) {
        const int i = (bid - 4352) * 256 + tid;
        ((half8*)whh0)[i] = mload(Whh0 + (size_t)i * 8, Mhh0 + (size_t)i * 8);
    } else if (bid < 5376) {
        const int i = (bid - 4864) * 256 + tid;
        ((half8*)wih1)[i] = mload(Wih1 + (size_t)i * 8, Mih1 + (size_t)i * 8);
    } else if (bid < 5888) {
        const int i = (bid - 5376) * 256 + tid;
        ((half8*)whh1)[i] = mload(Whh1 + (size_t)i * 8, Mhh1 + (size_t)i * 8);
    } else {
        const int i = (bid - 5888) * 256 + tid;
        if (i < G_) bs0[i] = bih0[i] + bhh0[i];
        else        bs1[i - G_] = bih1[i - G_] + bhh1[i - G_];
    }
}

// ------------------------------------------------------------ helpers -------
__device__ __forceinline__ float lstm_cell(float gi, float gf, float gg, float go,
                                           float& c) {
    const float i_ = 1.f / (1.f + __expf(-gi));
    const float f_ = 1.f / (1.f + __expf(-gf));
    const float gc = fminf(fmaxf(gg, -20.f), 20.f);
    const float e2 = __expf(2.f * gc);
    const float g_ = (e2 - 1.f) / (e2 + 1.f);
    const float o_ = 1.f / (1.f + __expf(-go));
    c = f_ * c + i_ * g_;
    const float cc  = fminf(fmaxf(c, -20.f), 20.f);
    const float e2c = __expf(2.f * cc);
    return o_ * (e2c - 1.f) / (e2c + 1.f);
}

// cross-layer __all poll over 32 flag lines (wave-level)
__device__ __forceinline__ void xpoll(const uint32_t* crossF, uint32_t tgt, int lane) {
    const uint32_t* p = crossF + (size_t)(lane & 31) * 16;
    while (true) {
        const uint32_t v = ald(p);
        if (__all((int)(v >= tgt))) break;
        __builtin_amdgcn_s_sleep(1);
    }
}

// -------------------------------------------------------- fused kernel ------
__global__ __launch_bounds__(256, 2) void fused_rnn(
    const float* __restrict__ x,
    const f16* __restrict__ xf16,    // per-island f16 x, or nullptr (fallback)
    const f16* __restrict__ Wih0, const f16* __restrict__ Whh0,
    const float* __restrict__ bs0,
    const f16* __restrict__ Wih1, const f16* __restrict__ Whh1,
    const float* __restrict__ bs1,
    float* __restrict__ dout,
    uint32_t* __restrict__ h0b,      // [8 isl][8 slots][2048 dw] f16 pairs
    uint32_t* __restrict__ h1b,      // [8 isl][2 slots][2048 dw]
    uint32_t* __restrict__ flags)    // [2 lay][8 isl][32 x 16 dw]
{
    __shared__ f16 bl0[8][520];            // B-operand: own-layer h
    __shared__ f16 bl1[8][520];            // B-operand: x (L0) or h0 (L1)
    __shared__ float glp[4][4][16][9];     // [wave][gate][jj][b] partials (pad 9)

    const int tid  = threadIdx.x;
    const int bid  = blockIdx.x;
    const int isl  = bid & 7;              // -> XCD under round-robin
    const int mem  = (bid >> 3) & 31;
    const int layer = bid >> 8;
    const int jb = mem * 16, b0 = isl * 8;
    const int wave = tid >> 6, lane = tid & 63, lm = lane & 15, quad = lane >> 4;
    const int eb = tid >> 4, ejj = tid & 15;
    const int hrow = lm < 8 ? lm : 7;      // cols 8..15 duplicate row 7 (discarded)

    uint32_t* ownF   = flags + (size_t)(layer * 8 + isl) * 512;
    uint32_t* crossF = flags + (size_t)((1 - layer) * 8 + isl) * 512;
    uint32_t* h0i = h0b + (size_t)isl * 8 * 2048;
    uint32_t* h1i = h1b + (size_t)isl * 2 * 2048;

    // per-thread sync: all 8 ring dwords of thread tid come from publisher
    // WG (tid>>3); poll only that flag. Own-WG data needs no poll (drained
    // at barD before our flag store).
    const uint32_t* myf = ownF + (size_t)(tid >> 3) * 16;
    const bool notown = (tid >> 3) != mem;

    if (layer == 0) {
        // ---- persistent A fragments: Whh0 (K=512 split over waves) + Wih0
        half8 ah[4][4], ai[4][2];
        {
            const int kb  = wave * 128 + quad * 8;
            const int kbx = wave * 64 + quad * 8;
#pragma unroll
            for (int gt = 0; gt < 4; ++gt) {
                const f16* wr = Whh0 + (size_t)(gt * 512 + jb + lm) * H_ + kb;
                const f16* xr = Wih0 + (size_t)(gt * 512 + jb + lm) * DIN_ + kbx;
#pragma unroll
                for (int kk = 0; kk < 4; ++kk) ah[gt][kk] = *(const half8*)(wr + kk * 32);
#pragma unroll
                for (int kk = 0; kk < 2; ++kk) ai[gt][kk] = *(const half8*)(xr + kk * 32);
            }
        }
        float bias[4];
#pragma unroll
        for (int g = 0; g < 4; ++g) bias[g] = bs0[g * 512 + jb + ejj];
        float c = 0.f;
        const f16* xfi = xf16 ? (xf16 + (size_t)isl * T_ * 2048) : (const f16*)nullptr;

        // ---- prologue: stage x[0] -> bl1
        if (xfi) {
            *(half8*)&bl1[tid >> 5][(tid & 31) * 8] =
                *(const half8*)(xfi + (tid >> 5) * 256 + (tid & 31) * 8);
        } else {
            const float* xp = x + (size_t)(b0 + (tid >> 5)) * T_ * DIN_ + (tid & 31) * 8;
            const float4 a = *(const float4*)xp;
            const float4 b = *(const float4*)(xp + 4);
            half8 h = { (f16)a.x, (f16)a.y, (f16)a.z, (f16)a.w,
                        (f16)b.x, (f16)b.y, (f16)b.z, (f16)b.w };
            *(half8*)&bl1[tid >> 5][(tid & 31) * 8] = h;
        }
        __syncthreads();

        for (int t = 0; t < T_; ++t) {
            // ---- per-thread progressive poll (publisher tid>>3 >= t)
            if (notown) {
                const uint32_t f0 = ald(myf);
                if (f0 < (uint32_t)t)
                    while (ald(myf) < (uint32_t)t) __builtin_amdgcn_s_sleep(1);
            }
            __builtin_amdgcn_sched_barrier(0);
            // ---- issue h0[t-1] ring reads (slot (t-1)&7); overlap with x-MFMAs
            uint32_t va[8];
            {
                const uint32_t* hb = h0i + (size_t)((t + 7) & 7) * 2048;
#pragma unroll
                for (int i = 0; i < 8; ++i) va[i] = ald(hb + i * 256 + tid);
            }
            floatx4 acc[4] = {};
            {
                const f16* br1 = &bl1[hrow][wave * 64 + quad * 8];
#pragma unroll
                for (int kk = 0; kk < 2; ++kk) {
                    const half8 bv = *(const half8*)(br1 + kk * 32);
#pragma unroll
                    for (int gt = 0; gt < 4; ++gt)
                        acc[gt] = __builtin_amdgcn_mfma_f32_16x16x32_f16(
                            ai[gt][kk], bv, acc[gt], 0, 0, 0);
                }
            }
            __builtin_amdgcn_sched_barrier(0);     // keep bl0 writes (vmcnt wait) after x-MFMAs
#pragma unroll
            for (int i = 0; i < 8; ++i) {
                const int u = i * 256 + tid;
                *(uint32_t*)&bl0[u >> 8][(u & 255) * 2] = va[i];
            }
            __syncthreads();                       // barB: bl0 ready
            {
                const f16* br0 = &bl0[hrow][wave * 128 + quad * 8];
#pragma unroll
                for (int kk = 0; kk < 4; ++kk) {
                    const half8 bv = *(const half8*)(br0 + kk * 32);
#pragma unroll
                    for (int gt = 0; gt < 4; ++gt)
                        acc[gt] = __builtin_amdgcn_mfma_f32_16x16x32_f16(
                            ah[gt][kk], bv, acc[gt], 0, 0, 0);
                }
            }
            if (lm < 8)
#pragma unroll
                for (int gt = 0; gt < 4; ++gt)
#pragma unroll
                    for (int r = 0; r < 4; ++r)
                        glp[wave][gt][quad * 4 + r][lm] = acc[gt][r];
            __syncthreads();                       // barC: glp ready, bl1 reads done
            if (tid < 128) {
                // ---- gate math + coalesced publish into ring slot t&7
                float gi = bias[0], gf = bias[1], gg = bias[2], go = bias[3];
#pragma unroll
                for (int w = 0; w < 4; ++w) {
                    gi += glp[w][0][ejj][eb]; gf += glp[w][1][ejj][eb];
                    gg += glp[w][2][ejj][eb]; go += glp[w][3][ejj][eb];
                }
                const float hn = lstm_cell(gi, gf, gg, go, c);
                const float ho = __shfl_xor(hn, 1);
                if (!(ejj & 1)) {
                    union { f16 h[2]; uint32_t u; } pk;
                    pk.h[0] = (f16)hn; pk.h[1] = (f16)ho;
                    ast(h0i + (size_t)(t & 7) * 2048 + (eb * H_ + jb + ejj) / 2, pk.u);
                }
            } else if (wave == 2) {
                // ---- restage bl1 <- x[t+1] (overlapped with gate math)
                const int tn = t + 1 < T_ ? t + 1 : t;
                if (xfi) {
                    const f16* src = xfi + (size_t)tn * 2048;
#pragma unroll
                    for (int j = 0; j < 4; ++j) {
                        const int o = j * 512 + lane * 8;
                        *(half8*)&bl1[o >> 8][o & 255] = *(const half8*)(src + o);
                    }
                } else {
#pragma unroll
                    for (int j = 0; j < 4; ++j) {
                        const int o = j * 512 + lane * 8;
                        const float* s = x + (size_t)(b0 + (o >> 8)) * T_ * DIN_
                                           + (size_t)tn * DIN_ + (o & 255);
                        const float4 a = *(const float4*)s;
                        const float4 b2 = *(const float4*)(s + 4);
                        half8 h = { (f16)a.x, (f16)a.y, (f16)a.z, (f16)a.w,
                                    (f16)b2.x, (f16)b2.y, (f16)b2.z, (f16)b2.w };
                        *(half8*)&bl1[o >> 8][o & 255] = h;
                    }
                }
            } else {
                // ---- wave 3: cross poll enabling NEXT iter's publish
                //      (slot (t+1)&7 overwrites h0[t-7]; L1 consumed at flag t-7)
                xpoll(crossF, t >= 7 ? (uint32_t)(t - 7) : 0u, lane);
            }
            __syncthreads();                       // barD: publish drained, bl1 staged
            if (tid == 0) ast(ownF + mem * 16, (uint32_t)(t + 1));
        }
    } else {
        // ---- layer 1: Whh1 + Wih1, both K=512, gates = h1.Whh1 + h0.Wih1
        half8 ah[4][4], ai[4][4];
        {
            const int kb = wave * 128 + quad * 8;
#pragma unroll
            for (int gt = 0; gt < 4; ++gt) {
                const f16* wr = Whh1 + (size_t)(gt * 512 + jb + lm) * H_ + kb;
                const f16* xr = Wih1 + (size_t)(gt * 512 + jb + lm) * H_ + kb;
#pragma unroll
                for (int kk = 0; kk < 4; ++kk) {
                    ah[gt][kk] = *(const half8*)(wr + kk * 32);
                    ai[gt][kk] = *(const half8*)(xr + kk * 32);
                }
            }
        }
        float bias[4];
#pragma unroll
        for (int g = 0; g < 4; ++g) bias[g] = bs1[g * 512 + jb + ejj];
        float c = 0.f;

        // ---- prologue: all threads poll their publisher's cross flag >= 2
        //      (covers h0[0] read now AND h0[1] staging during iter 0; the
        //      barrier joins => all 32 L0 WGs confirmed >= 2), stage h0[0]->bl1
        {
            const uint32_t* cf = crossF + (size_t)(tid >> 3) * 16;
            while (ald(cf) < 2u) __builtin_amdgcn_s_sleep(1);
            __builtin_amdgcn_sched_barrier(0);
            uint32_t vb[8];
#pragma unroll
            for (int i = 0; i < 8; ++i) vb[i] = ald(h0i + i * 256 + tid);
#pragma unroll
            for (int i = 0; i < 8; ++i) {
                const int u = i * 256 + tid;
                *(uint32_t*)&bl1[u >> 8][(u & 255) * 2] = vb[i];
            }
        }
        __syncthreads();

        for (int t = 0; t < T_; ++t) {
            // ---- per-thread progressive poll (publisher tid>>3 >= t)
            if (notown) {
                const uint32_t f0 = ald(myf);
                if (f0 < (uint32_t)t)
                    while (ald(myf) < (uint32_t)t) __builtin_amdgcn_s_sleep(1);
            }
            __builtin_amdgcn_sched_barrier(0);
            // ---- issue h1[t-1] ring reads (parity slot); overlap with ih-MFMAs
            uint32_t va[8];
            {
                const uint32_t* hb = h1i + (size_t)((t + 1) & 1) * 2048;
#pragma unroll
                for (int i = 0; i < 8; ++i) va[i] = ald(hb + i * 256 + tid);
            }
            floatx4 acc[4] = {};
            {
                const f16* br1 = &bl1[hrow][wave * 128 + quad * 8];
#pragma unroll
                for (int kk = 0; kk < 4; ++kk) {
                    const half8 bv = *(const half8*)(br1 + kk * 32);
#pragma unroll
                    for (int gt = 0; gt < 4; ++gt)
                        acc[gt] = __builtin_amdgcn_mfma_f32_16x16x32_f16(
                            ai[gt][kk], bv, acc[gt], 0, 0, 0);
                }
            }
            __builtin_amdgcn_sched_barrier(0);     // keep bl0 writes (vmcnt wait) after ih-MFMAs
#pragma unroll
            for (int i = 0; i < 8; ++i) {
                const int u = i * 256 + tid;
                *(uint32_t*)&bl0[u >> 8][(u & 255) * 2] = va[i];
            }
            __syncthreads();                       // barB: bl0 ready
            {
                const f16* br0 = &bl0[hrow][wave * 128 + quad * 8];
#pragma unroll
                for (int kk = 0; kk < 4; ++kk) {
                    const half8 bv = *(const half8*)(br0 + kk * 32);
#pragma unroll
                    for (int gt = 0; gt < 4; ++gt)
                        acc[gt] = __builtin_amdgcn_mfma_f32_16x16x32_f16(
                            ah[gt][kk], bv, acc[gt], 0, 0, 0);
                }
            }
            if (lm < 8)
#pragma unroll
                for (int gt = 0; gt < 4; ++gt)
#pragma unroll
                    for (int r = 0; r < 4; ++r)
                        glp[wave][gt][quad * 4 + r][lm] = acc[gt][r];
            __syncthreads();                       // barC: glp ready, bl1 reads done
            if (tid < 128) {
                float gi = bias[0], gf = bias[1], gg = bias[2], go = bias[3];
#pragma unroll
                for (int w = 0; w < 4; ++w) {
                    gi += glp[w][0][ejj][eb]; gf += glp[w][1][ejj][eb];
                    gg += glp[w][2][ejj][eb]; go += glp[w][3][ejj][eb];
                }
                const float hn = lstm_cell(gi, gf, gg, go, c);
                const float ho = __shfl_xor(hn, 1);
                if (!(ejj & 1)) {
                    union { f16 h[2]; uint32_t u; } pk;
                    pk.h[0] = (f16)hn; pk.h[1] = (f16)ho;
                    ast(h1i + (size_t)(t & 1) * 2048 + (eb * H_ + jb + ejj) / 2, pk.u);
                }
                if (t == T_ - 1)
                    dout[(size_t)(b0 + eb) * H_ + jb + ejj] = hn;
            } else {
                // ---- waves 2+3: restage bl1 <- h0[t+1] (ring slot (t+1)&7);
                //      flag >= t+2 was confirmed by wave3's poll in iter t-1
                if (t + 1 < T_) {
                    const uint32_t* gb = h0i + (size_t)((t + 1) & 7) * 2048;
                    const int jb4 = (wave == 2) ? 0 : 4;
#pragma unroll
                    for (int j = 0; j < 4; ++j) {
                        const int d0 = (jb4 + j) * 256 + lane;
                        const uint32_t w0 = ald(gb + d0);
                        const uint32_t w1 = ald(gb + d0 + 64);
                        const uint32_t w2 = ald(gb + d0 + 128);
                        const uint32_t w3 = ald(gb + d0 + 192);
                        *(uint32_t*)&bl1[jb4 + j][lane * 2]         = w0;
                        *(uint32_t*)&bl1[jb4 + j][(lane + 64) * 2]  = w1;
                        *(uint32_t*)&bl1[jb4 + j][(lane + 128) * 2] = w2;
                        *(uint32_t*)&bl1[jb4 + j][(lane + 192) * 2] = w3;
                    }
                }
                if (wave == 3) {
                    // cross poll: L0 >= t+3 enables staging h0[t+2] next iter
                    xpoll(crossF, (uint32_t)(t + 3 < T_ ? t + 3 : T_), lane);
                }
            }
            __syncthreads();                       // barD: publish drained, bl1 staged
            if (tid == 0) ast(ownF + mem * 16, (uint32_t)(t + 1));
        }
    }
}

// ------------------------------------------------------------ launcher ------
extern "C" void kernel_launch(void* const* d_in, const int* in_sizes, int n_in,
                              void* d_out, int out_size, void* d_ws, size_t ws_size,
                              hipStream_t stream) {
    const float* x    = (const float*)d_in[0];
    const float* Wih0 = (const float*)d_in[1];
    const float* Whh0 = (const float*)d_in[2];
    const float* bih0 = (const float*)d_in[3];
    const float* bhh0 = (const float*)d_in[4];
    const float* mih0 = (const float*)d_in[5];
    const float* mhh0 = (const float*)d_in[6];
    const float* Wih1 = (const float*)d_in[7];
    const float* Whh1 = (const float*)d_in[8];
    const float* bih1 = (const float*)d_in[9];
    const float* bhh1 = (const float*)d_in[10];
    const float* mih1 = (const float*)d_in[11];
    const float* mhh1 = (const float*)d_in[12];

    char* ws = (char*)d_ws;
    uint32_t* flags = (uint32_t*)(ws + OFF_FLAGS);
    uint32_t* h0b   = (uint32_t*)(ws + OFF_H0B);
    uint32_t* h1b   = (uint32_t*)(ws + OFF_H1B);
    f16*   wih0 = (f16*)(ws + OFF_WIH0);
    f16*   whh0 = (f16*)(ws + OFF_WHH0);
    f16*   wih1 = (f16*)(ws + OFF_WIH1);
    f16*   whh1 = (f16*)(ws + OFF_WHH1);
    float* bs0  = (float*)(ws + OFF_B0);
    float* bs1  = (float*)(ws + OFF_B1);
    const bool has_xf = (ws_size >= OFF_XF16 + XF16_BYTES);
    f16*   xf16 = has_xf ? (f16*)(ws + OFF_XF16) : (f16*)nullptr;
    float* out  = (float*)d_out;

    // zero flags + h rings (ws is re-poisoned before every timed call)
    hipMemsetAsync(ws, 0, ZERO_BYTES, stream);

    k_prep<<<5904, 256, 0, stream>>>(x, xf16,
                                     Wih0, mih0, Whh0, mhh0, bih0, bhh0,
                                     Wih1, mih1, Whh1, mhh1, bih1, bhh1,
                                     wih0, whh0, wih1, whh1, bs0, bs1);

    fused_rnn<<<512, 256, 0, stream>>>(x, xf16, wih0, whh0, bs0,
                                       wih1, whh1, bs1,
                                       out, h0b, h1b, flags);

    (void)in_sizes; (void)n_in; (void)out_size;
}

// Round 14
// 986.074 us; speedup vs baseline: 1.9252x; 1.9252x over previous
//
#include <hip/hip_runtime.h>
#include <cstdint>

// ---------------------------------------------------------------------------
// MaskedDeepRNN fused: 2-layer masked LSTM, B=64 T=512 D_IN=256 H=512 G=2048.
// R11 = R8 (best measured: 1014us harness) + per-lane early-exit poll.
//   R10 lesson: moving bl1 restage into the barC->barD window exposes ring
//   latency (window ~150cy << read ~300-900cy) -> reverted to R8 structure
//   where all ring reads issue right after barA and hide under the ih-MFMAs.
//   Poll tweak: per-lane exit (exec-masked) instead of __all full-reload --
//   satisfied lanes stop loading their flag line; tail spins touch only
//   straggler lines. Join semantics unchanged.
// Structure: 512 WGs (2/CU), islands of 32 WGs per 8-batch slice
// (blockIdx&7 -> XCD), L1 lags L0 via 8-slot L3 ring; merged 1-launch prep
// (xcast island-affine + w*m f16 + bias); split-phase MFMA overlap; L1
// register prefetch of h0[t+1]; glp reduction; wave0-only poll; 64B flags;
// 4 barriers/step.
// Ledger: all-wave poll -700 (R1/R2); 1 WG/CU -200 (R3); scattered publish
// -220 (R4); split-phase +60 (R5); xf16 L2-residency -330 fused (R6);
// per-island weight fold -555 fused (R7); merged prep +435 (R8);
// progressive sync / off-path staging -880 (R9/R10, reverted).
// ---------------------------------------------------------------------------

typedef _Float16 f16;
typedef _Float16 half8 __attribute__((ext_vector_type(8)));
typedef float floatx4 __attribute__((ext_vector_type(4)));

#define B_ 64
#define T_ 512
#define DIN_ 256
#define H_ 512
#define G_ 2048

// workspace layout (bytes)
static const size_t OFF_FLAGS = 0;                              // 2 lay x 8 isl x 32 flags x 64B = 32 KB
static const size_t OFF_H0B   = 32768;                          // 8 isl x 8 slots x 8KB = 512 KB
static const size_t OFF_H1B   = OFF_H0B + 524288;               // 8 isl x 2 slots x 8KB = 128 KB
static const size_t OFF_WIH0  = OFF_H1B + 131072;               // f16 weights
static const size_t OFF_WHH0  = OFF_WIH0 + (size_t)G_ * DIN_ * 2;
static const size_t OFF_WIH1  = OFF_WHH0 + (size_t)G_ * H_ * 2;
static const size_t OFF_WHH1  = OFF_WIH1 + (size_t)G_ * H_ * 2;
static const size_t OFF_B0    = OFF_WHH1 + (size_t)G_ * H_ * 2;
static const size_t OFF_B1    = OFF_B0 + 8192;
static const size_t OFF_XF16  = OFF_B1 + 8192;                  // 8 isl x 512 t x 8 b x 256 d x 2B
static const size_t XF16_BYTES = (size_t)8 * T_ * 8 * DIN_ * 2; // 16.78 MB
static const size_t ZERO_BYTES = OFF_WIH0;                      // flags + h rings

__device__ __forceinline__ uint32_t ald(const uint32_t* p) {
    return __hip_atomic_load(p, __ATOMIC_RELAXED, __HIP_MEMORY_SCOPE_AGENT);
}
__device__ __forceinline__ void ast(uint32_t* p, uint32_t v) {
    __hip_atomic_store(p, v, __ATOMIC_RELAXED, __HIP_MEMORY_SCOPE_AGENT);
}

// masked f16 half8 from f32 weight + f32 mask (8 consecutive elements)
__device__ __forceinline__ half8 mload(const float* w, const float* m) {
    const float4 a = *(const float4*)w, b = *(const float4*)(w + 4);
    const float4 c = *(const float4*)m, d = *(const float4*)(m + 4);
    half8 h = { (f16)(a.x * c.x), (f16)(a.y * c.y), (f16)(a.z * c.z), (f16)(a.w * c.w),
                (f16)(b.x * d.x), (f16)(b.y * d.y), (f16)(b.z * d.z), (f16)(b.w * d.w) };
    return h;
}

// ------------------------------------------------- merged prep (1 launch) ---
// blocks [0,4096):     xcast  x[b][t][d] f32 -> xf16[isl][t][b&7][d] f16,
//                      blockIdx&7 = isl -> writes land in island's XCD L2
// blocks [4096,4352):  Wih0*m -> f16
// blocks [4352,4864):  Whh0*m -> f16
// blocks [4864,5376):  Wih1*m -> f16
// blocks [5376,5888):  Whh1*m -> f16
// blocks [5888,5904):  biases
__global__ void k_prep(const float* __restrict__ x, f16* __restrict__ xf16,
                       const float* __restrict__ Wih0, const float* __restrict__ Mih0,
                       const float* __restrict__ Whh0, const float* __restrict__ Mhh0,
                       const float* __restrict__ bih0, const float* __restrict__ bhh0,
                       const float* __restrict__ Wih1, const float* __restrict__ Mih1,
                       const float* __restrict__ Whh1, const float* __restrict__ Mhh1,
                       const float* __restrict__ bih1, const float* __restrict__ bhh1,
                       f16* __restrict__ wih0, f16* __restrict__ whh0,
                       f16* __restrict__ wih1, f16* __restrict__ whh1,
                       float* __restrict__ bs0, float* __restrict__ bs1) {
    const int bid = blockIdx.x, tid = threadIdx.x;
    if (bid < 4096) {
        if (!xf16) return;
        const int isl = bid & 7, t = bid >> 3;
        const int b = tid >> 5, dq = tid & 31;
        const float* s = x + ((size_t)(isl * 8 + b) * T_ + t) * DIN_ + dq * 8;
        const float4 a  = *(const float4*)s;
        const float4 bb = *(const float4*)(s + 4);
        half8 h = { (f16)a.x, (f16)a.y, (f16)a.z, (f16)a.w,
                    (f16)bb.x, (f16)bb.y, (f16)bb.z, (f16)bb.w };
        *(half8*)(xf16 + ((size_t)(isl * 512 + t) * 8 + b) * 256 + dq * 8) = h;
    } else if (bid < 4352) {
        const int i = (bid - 4096) * 256 + tid;
        ((half8*)wih0)[i] = mload(Wih0 + (size_t)i * 8, Mih0 + (size_t)i * 8);
    } else if (bid < 4864) {
        const int i = (bid - 4352) * 256 + tid;
        ((half8*)whh0)[i] = mload(Whh0 + (size_t)i * 8, Mhh0 + (size_t)i * 8);
    } else if (bid < 5376) {
        const int i = (bid - 4864) * 256 + tid;
        ((half8*)wih1)[i] = mload(Wih1 + (size_t)i * 8, Mih1 + (size_t)i * 8);
    } else if (bid < 5888) {
        const int i = (bid - 5376) * 256 + tid;
        ((half8*)whh1)[i] = mload(Whh1 + (size_t)i * 8, Mhh1 + (size_t)i * 8);
    } else {
        const int i = (bid - 5888) * 256 + tid;
        if (i < G_) bs0[i] = bih0[i] + bhh0[i];
        else        bs1[i - G_] = bih1[i - G_] + bhh1[i - G_];
    }
}

// ------------------------------------------------------------ helpers -------
__device__ __forceinline__ void poll_flags(const uint32_t* ownF, uint32_t town,
                                           const uint32_t* crossF, uint32_t tcr,
                                           int lane) {
    // lanes 0..31 watch own-island flags, 32..63 the partner layer's island.
    // Per-lane early exit: satisfied lanes stop loading their flag line
    // (exec-masked); wave proceeds when all lanes have exited.
    const uint32_t* p = (lane < 32) ? (ownF + (size_t)lane * 16)
                                    : (crossF + (size_t)(lane - 32) * 16);
    const uint32_t tgt = (lane < 32) ? town : tcr;
    while (ald(p) < tgt) __builtin_amdgcn_s_sleep(1);
}

__device__ __forceinline__ float lstm_cell(float gi, float gf, float gg, float go,
                                           float& c) {
    const float i_ = 1.f / (1.f + __expf(-gi));
    const float f_ = 1.f / (1.f + __expf(-gf));
    const float gc = fminf(fmaxf(gg, -20.f), 20.f);
    const float e2 = __expf(2.f * gc);
    const float g_ = (e2 - 1.f) / (e2 + 1.f);
    const float o_ = 1.f / (1.f + __expf(-go));
    c = f_ * c + i_ * g_;
    const float cc  = fminf(fmaxf(c, -20.f), 20.f);
    const float e2c = __expf(2.f * cc);
    return o_ * (e2c - 1.f) / (e2c + 1.f);
}

// -------------------------------------------------------- fused kernel ------
__global__ __launch_bounds__(256, 2) void fused_rnn(
    const float* __restrict__ x,
    const f16* __restrict__ xf16,    // per-island f16 x, or nullptr (fallback)
    const f16* __restrict__ Wih0, const f16* __restrict__ Whh0,
    const float* __restrict__ bs0,
    const f16* __restrict__ Wih1, const f16* __restrict__ Whh1,
    const float* __restrict__ bs1,
    float* __restrict__ dout,
    uint32_t* __restrict__ h0b,      // [8 isl][8 slots][2048 dw] f16 pairs
    uint32_t* __restrict__ h1b,      // [8 isl][2 slots][2048 dw]
    uint32_t* __restrict__ flags)    // [2 lay][8 isl][32 x 16 dw]
{
    __shared__ f16 bl0[8][520];            // B-operand: own-layer h
    __shared__ f16 bl1[8][520];            // B-operand: x (L0) or h0 (L1)
    __shared__ float glp[4][4][16][9];     // [wave][gate][jj][b] partials (pad 9)

    const int tid  = threadIdx.x;
    const int bid  = blockIdx.x;
    const int isl  = bid & 7;              // -> XCD under round-robin
    const int mem  = (bid >> 3) & 31;
    const int layer = bid >> 8;
    const int jb = mem * 16, b0 = isl * 8;
    const int wave = tid >> 6, lane = tid & 63, lm = lane & 15, quad = lane >> 4;
    const int eb = tid >> 4, ejj = tid & 15;
    const int hrow = lm < 8 ? lm : 7;      // cols 8..15 duplicate row 7 (discarded)

    uint32_t* ownF   = flags + (size_t)(layer * 8 + isl) * 512;
    uint32_t* crossF = flags + (size_t)((1 - layer) * 8 + isl) * 512;
    uint32_t* h0i = h0b + (size_t)isl * 8 * 2048;
    uint32_t* h1i = h1b + (size_t)isl * 2 * 2048;

    if (layer == 0) {
        // ---- persistent A fragments: Whh0 (K=512 split over waves) + Wih0
        half8 ah[4][4], ai[4][2];
        {
            const int kb  = wave * 128 + quad * 8;
            const int kbx = wave * 64 + quad * 8;
#pragma unroll
            for (int gt = 0; gt < 4; ++gt) {
                const f16* wr = Whh0 + (size_t)(gt * 512 + jb + lm) * H_ + kb;
                const f16* xr = Wih0 + (size_t)(gt * 512 + jb + lm) * DIN_ + kbx;
#pragma unroll
                for (int kk = 0; kk < 4; ++kk) ah[gt][kk] = *(const half8*)(wr + kk * 32);
#pragma unroll
                for (int kk = 0; kk < 2; ++kk) ai[gt][kk] = *(const half8*)(xr + kk * 32);
            }
        }
        float bias[4];
#pragma unroll
        for (int g = 0; g < 4; ++g) bias[g] = bs0[g * 512 + jb + ejj];
        float c = 0.f;
        // x[t] slice: thread -> (batch=tid>>5, k0=(tid&31)*8)
        const f16* xs = xf16 ? (xf16 + (size_t)isl * T_ * 2048 +
                                (tid >> 5) * 256 + (tid & 31) * 8)
                             : nullptr;
        const float* xp = x + (size_t)(b0 + (tid >> 5)) * T_ * DIN_ + (tid & 31) * 8;
        half8 xcur;
        if (xs) {
            xcur = *(const half8*)xs;                      // x[0], L2-warm from prep
        } else {
            const float4 a = *(const float4*)xp;
            const float4 b = *(const float4*)(xp + 4);
            xcur = { (f16)a.x, (f16)a.y, (f16)a.z, (f16)a.w,
                     (f16)b.x, (f16)b.y, (f16)b.z, (f16)b.w };
        }

        for (int t = 0; t < T_; ++t) {
            // ---- loop top: stage x[t] into bl1 (no flag dependency), then
            //      load x[t+1]; the load drains at barA under wave0's poll
            *(half8*)&bl1[tid >> 5][(tid & 31) * 8] = xcur;
            {
                const int tn = t + 1 < T_ ? t + 1 : t;
                if (xs) {
                    xcur = *(const half8*)(xs + (size_t)tn * 2048);
                } else {
                    const float4 a = *(const float4*)(xp + (size_t)tn * DIN_);
                    const float4 b = *(const float4*)(xp + (size_t)tn * DIN_ + 4);
                    xcur = { (f16)a.x, (f16)a.y, (f16)a.z, (f16)a.w,
                             (f16)b.x, (f16)b.y, (f16)b.z, (f16)b.w };
                }
            }
            // own peers done with step t-1; L1 done with step t-8 (ring safety)
            if (wave == 0)
                poll_flags(ownF, (uint32_t)t, crossF,
                           t >= 7 ? (uint32_t)(t - 7) : 0u, lane);
            __syncthreads();                       // barA: bl1 ready + poll done
            // ---- issue h0[t-1] ring reads (slot (t-1)&7), overlap with x-MFMAs
            uint32_t va[8];
            {
                const uint32_t* hb = h0i + (size_t)((t + 7) & 7) * 2048;
#pragma unroll
                for (int i = 0; i < 8; ++i) va[i] = ald(hb + i * 256 + tid);
            }
            floatx4 acc[4] = {};
            {
                const f16* br1 = &bl1[hrow][wave * 64 + quad * 8];
#pragma unroll
                for (int kk = 0; kk < 2; ++kk) {
                    const half8 bv = *(const half8*)(br1 + kk * 32);
#pragma unroll
                    for (int gt = 0; gt < 4; ++gt)
                        acc[gt] = __builtin_amdgcn_mfma_f32_16x16x32_f16(
                            ai[gt][kk], bv, acc[gt], 0, 0, 0);
                }
            }
            __builtin_amdgcn_sched_barrier(0);     // keep bl0 writes (vmcnt wait) after x-MFMAs
            // ---- stage h0[t-1] into bl0 (waits on va loads)
#pragma unroll
            for (int i = 0; i < 8; ++i) {
                const int u = i * 256 + tid;
                *(uint32_t*)&bl0[u >> 8][(u & 255) * 2] = va[i];
            }
            __syncthreads();                       // barB: bl0 ready
            {
                const f16* br0 = &bl0[hrow][wave * 128 + quad * 8];
#pragma unroll
                for (int kk = 0; kk < 4; ++kk) {
                    const half8 bv = *(const half8*)(br0 + kk * 32);
#pragma unroll
                    for (int gt = 0; gt < 4; ++gt)
                        acc[gt] = __builtin_amdgcn_mfma_f32_16x16x32_f16(
                            ah[gt][kk], bv, acc[gt], 0, 0, 0);
                }
            }
            if (lm < 8)
#pragma unroll
                for (int gt = 0; gt < 4; ++gt)
#pragma unroll
                    for (int r = 0; r < 4; ++r)
                        glp[wave][gt][quad * 4 + r][lm] = acc[gt][r];
            __syncthreads();                       // barC: glp ready
            // ---- gate math + coalesced publish into ring slot t&7
            if (tid < 128) {
                float gi = bias[0], gf = bias[1], gg = bias[2], go = bias[3];
#pragma unroll
                for (int w = 0; w < 4; ++w) {
                    gi += glp[w][0][ejj][eb]; gf += glp[w][1][ejj][eb];
                    gg += glp[w][2][ejj][eb]; go += glp[w][3][ejj][eb];
                }
                const float hn = lstm_cell(gi, gf, gg, go, c);
                const float ho = __shfl_xor(hn, 1);
                if (!(ejj & 1)) {
                    union { f16 h[2]; uint32_t u; } pk;
                    pk.h[0] = (f16)hn; pk.h[1] = (f16)ho;
                    ast(h0i + (size_t)(t & 7) * 2048 + (eb * H_ + jb + ejj) / 2, pk.u);
                }
            }
            __syncthreads();                       // barD: drains h stores
            if (tid == 0) ast(ownF + mem * 16, (uint32_t)(t + 1));
        }
    } else {
        // ---- layer 1: Whh1 + Wih1, both K=512, gates = h1.Whh1 + h0.Wih1
        half8 ah[4][4], ai[4][4];
        {
            const int kb = wave * 128 + quad * 8;
#pragma unroll
            for (int gt = 0; gt < 4; ++gt) {
                const f16* wr = Whh1 + (size_t)(gt * 512 + jb + lm) * H_ + kb;
                const f16* xr = Wih1 + (size_t)(gt * 512 + jb + lm) * H_ + kb;
#pragma unroll
                for (int kk = 0; kk < 4; ++kk) {
                    ah[gt][kk] = *(const half8*)(wr + kk * 32);
                    ai[gt][kk] = *(const half8*)(xr + kk * 32);
                }
            }
        }
        float bias[4];
#pragma unroll
        for (int g = 0; g < 4; ++g) bias[g] = bs1[g * 512 + jb + ejj];
        float c = 0.f;

        // ---- prologue: fetch h0[0] into regs (needs L0 flag >= 1)
        uint32_t vb[8];
        if (wave == 0) poll_flags(ownF, 0u, crossF, 1u, lane);
        __syncthreads();
#pragma unroll
        for (int i = 0; i < 8; ++i) vb[i] = ald(h0i + i * 256 + tid);

        for (int t = 0; t < T_; ++t) {
            // ---- loop top: stage h0[t] into bl1 from prefetched regs
#pragma unroll
            for (int i = 0; i < 8; ++i) {
                const int u = i * 256 + tid;
                *(uint32_t*)&bl1[u >> 8][(u & 255) * 2] = vb[i];
            }
            // own peers done with t-1; L0 >= t+2 so h0[t+1] is published
            if (wave == 0)
                poll_flags(ownF, (uint32_t)t, crossF,
                           (uint32_t)(t + 2 < T_ ? t + 2 : T_), lane);
            __syncthreads();                       // barA: bl1 ready + poll done
            // ---- issue h1[t-1] reads + prefetch h0[t+1]; overlap with ih-MFMAs
            uint32_t va[8];
            {
                const uint32_t* hb = h1i + (size_t)((t + 1) & 1) * 2048;
#pragma unroll
                for (int i = 0; i < 8; ++i) va[i] = ald(hb + i * 256 + tid);
                const uint32_t* gb = h0i + (size_t)((t + 1) & 7) * 2048;
#pragma unroll
                for (int i = 0; i < 8; ++i) vb[i] = ald(gb + i * 256 + tid);
            }
            floatx4 acc[4] = {};
            {
                const f16* br1 = &bl1[hrow][wave * 128 + quad * 8];
#pragma unroll
                for (int kk = 0; kk < 4; ++kk) {
                    const half8 bv = *(const half8*)(br1 + kk * 32);
#pragma unroll
                    for (int gt = 0; gt < 4; ++gt)
                        acc[gt] = __builtin_amdgcn_mfma_f32_16x16x32_f16(
                            ai[gt][kk], bv, acc[gt], 0, 0, 0);
                }
            }
            __builtin_amdgcn_sched_barrier(0);     // keep bl0 writes (vmcnt wait) after ih-MFMAs
            // ---- stage h1[t-1] into bl0 (waits on va loads)
#pragma unroll
            for (int i = 0; i < 8; ++i) {
                const int u = i * 256 + tid;
                *(uint32_t*)&bl0[u >> 8][(u & 255) * 2] = va[i];
            }
            __syncthreads();                       // barB: bl0 ready
            {
                const f16* br0 = &bl0[hrow][wave * 128 + quad * 8];
#pragma unroll
                for (int kk = 0; kk < 4; ++kk) {
                    const half8 bv = *(const half8*)(br0 + kk * 32);
#pragma unroll
                    for (int gt = 0; gt < 4; ++gt)
                        acc[gt] = __builtin_amdgcn_mfma_f32_16x16x32_f16(
                            ah[gt][kk], bv, acc[gt], 0, 0, 0);
                }
            }
            if (lm < 8)
#pragma unroll
                for (int gt = 0; gt < 4; ++gt)
#pragma unroll
                    for (int r = 0; r < 4; ++r)
                        glp[wave][gt][quad * 4 + r][lm] = acc[gt][r];
            __syncthreads();                       // barC: glp ready
            if (tid < 128) {
                float gi = bias[0], gf = bias[1], gg = bias[2], go = bias[3];
#pragma unroll
                for (int w = 0; w < 4; ++w) {
                    gi += glp[w][0][ejj][eb]; gf += glp[w][1][ejj][eb];
                    gg += glp[w][2][ejj][eb]; go += glp[w][3][ejj][eb];
                }
                const float hn = lstm_cell(gi, gf, gg, go, c);
                const float ho = __shfl_xor(hn, 1);
                if (!(ejj & 1)) {
                    union { f16 h[2]; uint32_t u; } pk;
                    pk.h[0] = (f16)hn; pk.h[1] = (f16)ho;
                    ast(h1i + (size_t)(t & 1) * 2048 + (eb * H_ + jb + ejj) / 2, pk.u);
                }
                if (t == T_ - 1)
                    dout[(size_t)(b0 + eb) * H_ + jb + ejj] = hn;
            }
            __syncthreads();                       // barD: drains h stores
            if (tid == 0) ast(ownF + mem * 16, (uint32_t)(t + 1));
        }
    }
}

// ------------------------------------------------------------ launcher ------
extern "C" void kernel_launch(void* const* d_in, const int* in_sizes, int n_in,
                              void* d_out, int out_size, void* d_ws, size_t ws_size,
                              hipStream_t stream) {
    const float* x    = (const float*)d_in[0];
    const float* Wih0 = (const float*)d_in[1];
    const float* Whh0 = (const float*)d_in[2];
    const float* bih0 = (const float*)d_in[3];
    const float* bhh0 = (const float*)d_in[4];
    const float* mih0 = (const float*)d_in[5];
    const float* mhh0 = (const float*)d_in[6];
    const float* Wih1 = (const float*)d_in[7];
    const float* Whh1 = (const float*)d_in[8];
    const float* bih1 = (const float*)d_in[9];
    const float* bhh1 = (const float*)d_in[10];
    const float* mih1 = (const float*)d_in[11];
    const float* mhh1 = (const float*)d_in[12];

    char* ws = (char*)d_ws;
    uint32_t* flags = (uint32_t*)(ws + OFF_FLAGS);
    uint32_t* h0b   = (uint32_t*)(ws + OFF_H0B);
    uint32_t* h1b   = (uint32_t*)(ws + OFF_H1B);
    f16*   wih0 = (f16*)(ws + OFF_WIH0);
    f16*   whh0 = (f16*)(ws + OFF_WHH0);
    f16*   wih1 = (f16*)(ws + OFF_WIH1);
    f16*   whh1 = (f16*)(ws + OFF_WHH1);
    float* bs0  = (float*)(ws + OFF_B0);
    float* bs1  = (float*)(ws + OFF_B1);
    const bool has_xf = (ws_size >= OFF_XF16 + XF16_BYTES);
    f16*   xf16 = has_xf ? (f16*)(ws + OFF_XF16) : (f16*)nullptr;
    float* out  = (float*)d_out;

    // zero flags + h rings (ws is re-poisoned before every timed call)
    hipMemsetAsync(ws, 0, ZERO_BYTES, stream);

    k_prep<<<5904, 256, 0, stream>>>(x, xf16,
                                     Wih0, mih0, Whh0, mhh0, bih0, bhh0,
                                     Wih1, mih1, Whh1, mhh1, bih1, bhh1,
                                     wih0, whh0, wih1, whh1, bs0, bs1);

    fused_rnn<<<512, 256, 0, stream>>>(x, xf16, wih0, whh0, bs0,
                                       wih1, whh1, bs1,
                                       out, h0b, h1b, flags);

    (void)in_sizes; (void)n_in; (void)out_size;
}